// Round 9
// baseline (174.366 us; speedup 1.0000x reference)
//
#include <hip/hip_runtime.h>
#include <hip/hip_bf16.h>
#include <math.h>

#define BB 2
#define SS 2048
#define DD 1024
#define HH 16
#define HDIM 64

typedef unsigned short u16;
typedef __attribute__((ext_vector_type(8))) short bfrag;   // 8 bf16 = 4 VGPRs
typedef __attribute__((ext_vector_type(4))) short s16x4;   // 4 bf16 = 2 VGPRs
typedef __attribute__((ext_vector_type(4))) float f32x4;

#define NEG_BIG (-1e30f)
// 1/sqrt(64) * log2(e): folded into Q so attention uses exp2 directly
#define QSCALE 0.18033688011112042f

__device__ __forceinline__ u16 f2u(float f) {
    unsigned int u = __builtin_bit_cast(unsigned int, f);
    u += 0x7fffu + ((u >> 16) & 1u);
    return (u16)(u >> 16);
}

__device__ __forceinline__ float fexp2(float x) {
#if __has_builtin(__builtin_amdgcn_exp2f)
    return __builtin_amdgcn_exp2f(x);   // raw v_exp_f32 (TRANS pipe, 1 instr)
#else
    return exp2f(x);
#endif
}

__device__ __forceinline__ void async16(const u16* g, u16* l) {
    __builtin_amdgcn_global_load_lds((__attribute__((address_space(1))) void*)g,
                                     (__attribute__((address_space(3))) void*)l,
                                     16, 0, 0);
}

__device__ __forceinline__ f32x4 mfma16(bfrag a, bfrag b, f32x4 c) {
    return __builtin_amdgcn_mfma_f32_16x16x32_bf16(a, b, c, 0, 0, 0);
}

// 16x16x16 bf16 MFMA: builtin name differs across ROCm; dispatch at compile time.
__device__ __forceinline__ f32x4 mfma_pv(s16x4 a, s16x4 b, f32x4 c) {
#if __has_builtin(__builtin_amdgcn_mfma_f32_16x16x16_bf16)
    return __builtin_amdgcn_mfma_f32_16x16x16_bf16(a, b, c, 0, 0, 0);
#elif __has_builtin(__builtin_amdgcn_mfma_f32_16x16x16bf16_1k)
    return __builtin_amdgcn_mfma_f32_16x16x16bf16_1k(a, b, c, 0, 0, 0);
#else
    f32x4 d;
    asm("v_mfma_f32_16x16x16_bf16 %0, %1, %2, %3" : "=v"(d) : "v"(a), "v"(b), "v"(c));
    return d;
#endif
}

// ---------------------------------------------------------------------------
// prep: fused cvt_x + cvt_wT (round-0 verbatim).
// ---------------------------------------------------------------------------
__global__ __launch_bounds__(256) void prep_k(
    const float* __restrict__ x,  u16* __restrict__ xb,
    const float* __restrict__ wq, const float* __restrict__ wk,
    const float* __restrict__ wv, const float* __restrict__ wo,
    u16* __restrict__ wT)
{
    const int id = blockIdx.x;
    const int t = threadIdx.x;
    if (id < 2048) {
        int i = (id * 256 + t) * 8;
        float4 a = *(const float4*)(x + i);
        float4 b = *(const float4*)(x + i + 4);
        u16 o[8] = { f2u(a.x), f2u(a.y), f2u(a.z), f2u(a.w),
                     f2u(b.x), f2u(b.y), f2u(b.z), f2u(b.w) };
        *(uint4*)(xb + i) = *(uint4*)o;
        return;
    }
    const int wid = id - 2048;
    const int z = wid >> 8;
    const int kt = wid & 15, nt = (wid >> 4) & 15;
    const float* w = (z == 0) ? wq : (z == 1) ? wk : (z == 2) ? wv : wo;
    u16* o = wT + (size_t)z * DD * DD;
    __shared__ __align__(16) u16 T[64][72];
    const int k0 = kt * 64, n0 = nt * 64;
    {
        int kr = t >> 2, nb = (t & 3) * 16;
        const float4* s4 = (const float4*)(w + (size_t)(k0 + kr) * DD + n0 + nb);
        #pragma unroll
        for (int jj = 0; jj < 4; ++jj) {
            float4 v = s4[jj];
            T[kr][nb + jj*4 + 0] = f2u(v.x);
            T[kr][nb + jj*4 + 1] = f2u(v.y);
            T[kr][nb + jj*4 + 2] = f2u(v.z);
            T[kr][nb + jj*4 + 3] = f2u(v.w);
        }
    }
    __syncthreads();
    {
        int nr = t >> 2, kb = (t & 3) * 16;
        u16 tmp[16];
        #pragma unroll
        for (int j = 0; j < 16; ++j) tmp[j] = T[kb + j][nr];
        *(uint4*)(o + (size_t)(n0 + nr) * DD + k0 + kb)     = ((uint4*)tmp)[0];
        *(uint4*)(o + (size_t)(n0 + nr) * DD + k0 + kb + 8) = ((uint4*)tmp)[1];
    }
}

// ===========================================================================
// QKV GEMM (round-0 verbatim): BM=128, BN=64, BK=64 -> 1536 blocks.
// ===========================================================================
__global__ __launch_bounds__(256) void gemm_qkv_k(
    const u16* __restrict__ xb, const u16* __restrict__ wT,
    u16* __restrict__ Qo, u16* __restrict__ Ko, u16* __restrict__ Vt)
{
    const u16* wTz = wT + (size_t)blockIdx.z * DD * DD;
    const float osc = (blockIdx.z == 0) ? QSCALE : 1.0f;

    __shared__ __align__(16) u16 As[128 * 64];   // 16 KB
    __shared__ __align__(16) u16 Bs[64 * 64];    // 8 KB

    const int t = threadIdx.x;
    const int m0 = blockIdx.x * 128, n0 = blockIdx.y * 64;
    const int lane15 = t & 15, quad = (t >> 4) & 3, wave = t >> 6;
    const int wm = wave & 1, wn = wave >> 1;

    int arow[4], acol[4];
    #pragma unroll
    for (int i = 0; i < 4; ++i) {
        int c = t + i * 256;
        arow[i] = c >> 3;
        acol[i] = (c & 7) ^ (arow[i] & 7);
    }
    const int br0 = t >> 3,         bs0 = t & 7;
    const int br1 = (t + 256) >> 3, bs1 = (t + 256) & 7;
    const int bc0 = bs0 ^ (br0 & 7);
    const int bc1 = bs1 ^ (br1 & 7);
    const int ldb = (t & 192) * 8;

    int aoff[4][2], boff[2][2];
    #pragma unroll
    for (int mi = 0; mi < 4; ++mi) {
        int r = wm * 64 + mi * 16 + lane15;
        #pragma unroll
        for (int kh = 0; kh < 2; ++kh)
            aoff[mi][kh] = (r * 8 + ((kh * 4 + quad) ^ (r & 7))) * 8;
    }
    #pragma unroll
    for (int ni = 0; ni < 2; ++ni) {
        int r = wn * 32 + ni * 16 + lane15;
        #pragma unroll
        for (int kh = 0; kh < 2; ++kh)
            boff[ni][kh] = (r * 8 + ((kh * 4 + quad) ^ (r & 7))) * 8;
    }

    f32x4 acc[4][2];
    #pragma unroll
    for (int mi = 0; mi < 4; ++mi)
        #pragma unroll
        for (int ni = 0; ni < 2; ++ni)
            acc[mi][ni] = (f32x4){0.f, 0.f, 0.f, 0.f};

    for (int it = 0; it < 16; ++it) {
        const int k0 = it * 64;
        #pragma unroll
        for (int i = 0; i < 4; ++i)
            async16(xb + (size_t)(m0 + arow[i]) * DD + k0 + acol[i] * 8,
                    As + ldb + i * 2048);
        async16(wTz + (size_t)(n0 + br0) * DD + k0 + bc0 * 8, Bs + ldb);
        async16(wTz + (size_t)(n0 + br1) * DD + k0 + bc1 * 8, Bs + ldb + 2048);
        __syncthreads();
        #pragma unroll
        for (int kh = 0; kh < 2; ++kh) {
            bfrag av[4], bv[2];
            #pragma unroll
            for (int mi = 0; mi < 4; ++mi) av[mi] = *(const bfrag*)(As + aoff[mi][kh]);
            #pragma unroll
            for (int ni = 0; ni < 2; ++ni) bv[ni] = *(const bfrag*)(Bs + boff[ni][kh]);
            #pragma unroll
            for (int mi = 0; mi < 4; ++mi)
                #pragma unroll
                for (int ni = 0; ni < 2; ++ni)
                    acc[mi][ni] = mfma16(av[mi], bv[ni], acc[mi][ni]);
        }
        __syncthreads();
    }

    const int h = n0 >> 6;
    const int bq = m0 >> 11;
    const int ms = m0 & (SS - 1);

    if (blockIdx.z != 2) {
        u16* out = (blockIdx.z == 0) ? Qo : Ko;
        u16* dst = out + (((size_t)(bq * HH + h)) * SS) * HDIM;
        #pragma unroll
        for (int mi = 0; mi < 4; ++mi) {
            #pragma unroll
            for (int r = 0; r < 4; ++r) {
                int s = ms + wm * 64 + mi * 16 + quad * 4 + r;
                #pragma unroll
                for (int ni = 0; ni < 2; ++ni) {
                    int hd = wn * 32 + ni * 16 + lane15;
                    dst[(size_t)s * HDIM + hd] = f2u(acc[mi][ni][r] * osc);
                }
            }
        }
    } else {
        u16* T = As;
        __syncthreads();
        #pragma unroll
        for (int mi = 0; mi < 4; ++mi)
            #pragma unroll
            for (int r = 0; r < 4; ++r) {
                int ml = wm * 64 + mi * 16 + quad * 4 + r;
                #pragma unroll
                for (int ni = 0; ni < 2; ++ni) {
                    int nl = wn * 32 + ni * 16 + lane15;
                    T[nl * 128 + (ml ^ ((nl & 7) << 4))] = f2u(acc[mi][ni][r]);
                }
            }
        __syncthreads();
        u16* dst = Vt + ((size_t)(bq * HH + h)) * (HDIM * SS);
        #pragma unroll
        for (int i = 0; i < 4; ++i) {
            int c = t + i * 256;
            int row = c >> 4;
            int mb  = (c & 15) * 8;
            uint4 val = *(const uint4*)&T[row * 128 + (mb ^ ((row & 7) << 4))];
            *(uint4*)(dst + (size_t)row * SS + ms + mb) = val;
        }
    }
}

// ---------------------------------------------------------------------------
// Out projection (round-0 verbatim): BM=64, BN=64, BK=128 -> grid (64,16).
// ---------------------------------------------------------------------------
__global__ __launch_bounds__(256) void gemm_out_k(
    const u16* __restrict__ ctxb, const u16* __restrict__ woT,
    const float* __restrict__ bo, float* __restrict__ out)
{
    __shared__ __align__(16) u16 As[2][4096];    // [k-half][64x64]
    __shared__ __align__(16) u16 Bs[2][4096];

    const int t = threadIdx.x;
    const int m0 = blockIdx.x * 64, n0 = blockIdx.y * 64;
    const int lane15 = t & 15, quad = (t >> 4) & 3, wave = t >> 6;
    const int wm = wave & 1, wn = wave >> 1;

    const int br0 = t >> 3,         bs0 = t & 7;
    const int br1 = (t + 256) >> 3, bs1 = (t + 256) & 7;
    const int bc0 = bs0 ^ (br0 & 7);
    const int bc1 = bs1 ^ (br1 & 7);
    const int ldb = (t & 192) * 8;

    int aoff[2][2], boff[2][2];
    #pragma unroll
    for (int mi = 0; mi < 2; ++mi) {
        int r = wm * 32 + mi * 16 + lane15;
        #pragma unroll
        for (int kh = 0; kh < 2; ++kh)
            aoff[mi][kh] = (r * 8 + ((kh * 4 + quad) ^ (r & 7))) * 8;
    }
    #pragma unroll
    for (int ni = 0; ni < 2; ++ni) {
        int r = wn * 32 + ni * 16 + lane15;
        #pragma unroll
        for (int kh = 0; kh < 2; ++kh)
            boff[ni][kh] = (r * 8 + ((kh * 4 + quad) ^ (r & 7))) * 8;
    }

    f32x4 acc[2][2];
    #pragma unroll
    for (int mi = 0; mi < 2; ++mi)
        #pragma unroll
        for (int ni = 0; ni < 2; ++ni)
            acc[mi][ni] = (f32x4){0.f, 0.f, 0.f, 0.f};

    for (int it = 0; it < 8; ++it) {
        const int k0 = it * 128;
        #pragma unroll
        for (int hh = 0; hh < 2; ++hh) {
            const int kh64 = k0 + hh * 64;
            async16(ctxb + (size_t)(m0 + br0) * DD + kh64 + bc0 * 8, &As[hh][ldb]);
            async16(ctxb + (size_t)(m0 + br1) * DD + kh64 + bc1 * 8, &As[hh][ldb + 2048]);
            async16(woT  + (size_t)(n0 + br0) * DD + kh64 + bc0 * 8, &Bs[hh][ldb]);
            async16(woT  + (size_t)(n0 + br1) * DD + kh64 + bc1 * 8, &Bs[hh][ldb + 2048]);
        }
        __syncthreads();
        #pragma unroll
        for (int hh = 0; hh < 2; ++hh) {
            #pragma unroll
            for (int kh = 0; kh < 2; ++kh) {
                bfrag av[2], bv[2];
                #pragma unroll
                for (int mi = 0; mi < 2; ++mi) av[mi] = *(const bfrag*)&As[hh][aoff[mi][kh]];
                #pragma unroll
                for (int ni = 0; ni < 2; ++ni) bv[ni] = *(const bfrag*)&Bs[hh][boff[ni][kh]];
                #pragma unroll
                for (int mi = 0; mi < 2; ++mi)
                    #pragma unroll
                    for (int ni = 0; ni < 2; ++ni)
                        acc[mi][ni] = mfma16(av[mi], bv[ni], acc[mi][ni]);
            }
        }
        __syncthreads();
    }

    float bias[2];
    #pragma unroll
    for (int ni = 0; ni < 2; ++ni)
        bias[ni] = bo[n0 + wn * 32 + ni * 16 + lane15];

    #pragma unroll
    for (int mi = 0; mi < 2; ++mi) {
        #pragma unroll
        for (int r = 0; r < 4; ++r) {
            int m = m0 + wm * 32 + mi * 16 + quad * 4 + r;
            #pragma unroll
            for (int ni = 0; ni < 2; ++ni) {
                int n = n0 + wn * 32 + ni * 16 + lane15;
                out[(size_t)m * DD + n] = acc[mi][ni][r] + bias[ni];
            }
        }
    }
}

// ===========================================================================
// MFMA flash attention — 128-row Q-tile (8 waves, 512 threads).
// Each staged 64-wide K/V tile feeds 128 q rows: per-CU block-iterations
// drop 66 -> 34 (fixed per-iter latency amortized 2x) while waves/SIMD
// stays 4 (2 blocks/CU x 8 waves). Counted-vmcnt depth-2, two buffers.
// Diagonal spans two tiles: kt=2*qt2 masked for all; kt=2*qt2+1 computed
// only by waves 4..7 (wave-uniform branch). Balanced pairs {15-y0, y0}.
// ===========================================================================
template<bool MASKED>
__device__ __forceinline__ void qkt_pv(
    const u16* __restrict__ Kc, const u16* __restrict__ Vc,
    const bfrag bq[2], const int koff[2], const int voff[4],
    int kv0, int qg, int quad4, f32x4 acc_o[4], f32x4& acc_s, s16x4 ones4)
{
    f32x4 sT[4];
    #pragma unroll
    for (int ni = 0; ni < 4; ++ni) sT[ni] = (f32x4){0.f, 0.f, 0.f, 0.f};

    __builtin_amdgcn_s_setprio(1);
    #pragma unroll
    for (int kh = 0; kh < 2; ++kh)
        #pragma unroll
        for (int ni = 0; ni < 4; ++ni)
            sT[ni] = mfma16(*(const bfrag*)&Kc[koff[kh] + ni * 1024], bq[kh], sT[ni]);
    __builtin_amdgcn_s_setprio(0);

    #pragma unroll
    for (int ni = 0; ni < 4; ++ni) {
        float pv[4];
        #pragma unroll
        for (int r = 0; r < 4; ++r) {
            float v = sT[ni][r];
            if (MASKED) {
                int kvg = kv0 + ni * 16 + quad4 + r;
                if (kvg > qg) v = NEG_BIG;
            }
            pv[r] = fexp2(v);
        }
        unsigned lo = __builtin_amdgcn_perm(
            __builtin_bit_cast(unsigned, pv[1]),
            __builtin_bit_cast(unsigned, pv[0]), 0x07060302u);
        unsigned hi = __builtin_amdgcn_perm(
            __builtin_bit_cast(unsigned, pv[3]),
            __builtin_bit_cast(unsigned, pv[2]), 0x07060302u);
        s16x4 pf = __builtin_bit_cast(s16x4,
            ((unsigned long long)hi << 32) | (unsigned long long)lo);
        __builtin_amdgcn_s_setprio(1);
        acc_s = mfma_pv(ones4, pf, acc_s);
        #pragma unroll
        for (int nd = 0; nd < 4; ++nd)
            acc_o[nd] = mfma_pv(*(const s16x4*)&Vc[voff[ni] + nd * 1024],
                                pf, acc_o[nd]);
        __builtin_amdgcn_s_setprio(0);
    }
}

__global__ __launch_bounds__(512, 4) void attn_k(
    const u16* __restrict__ Q, const u16* __restrict__ K,
    const u16* __restrict__ Vt, u16* __restrict__ ctx)
{
    __shared__ __align__(16) u16 Ks[2][64 * 64];   // 16 KB
    __shared__ __align__(16) u16 Vs[2][64 * 64];   // 16 KB
    const int t = threadIdx.x;
    const int lane15 = t & 15, quad = (t >> 4) & 3, wave = t >> 6;   // wave 0..7
    const int bh = blockIdx.x;
    // balanced pairing: first dispatch round (y 0..7) gets qt2 = 15-y0 (long),
    // second (y 8..15) gets qt2 = y0 (short) -> per-CU iters = 34 constant.
    const int yy = (int)blockIdx.y;
    const int y0 = yy & 7;
    const int qt2 = (yy >> 3) ? y0 : 15 - y0;
    const int q0 = qt2 * 128;
    const int b = bh >> 4, h = bh & 15;
    const u16* Qb = Q  + (size_t)bh * SS * HDIM;
    const u16* Kb = K  + (size_t)bh * SS * HDIM;
    const u16* Vb = Vt + (size_t)bh * HDIM * SS;

    // staging map: 512 threads x 16B = one full 64x64 bf16 tile per buffer.
    // thread t -> row t>>3, global col slot (t&7)^(row&7); LDS dest linear
    // (DMA = wave base + lane*16), source pre-swizzled (both-sides rule).
    const int kr0 = t >> 3, ks0 = t & 7;
    const int kc0 = ks0 ^ (kr0 & 7);
    const int ldst = (t & 448) * 8;     // wave*512 u16 (wave-uniform base)

    const u16* kga = Kb + (size_t)kr0 * HDIM + kc0 * 8;
    const u16* vga = Vb + (size_t)kr0 * SS + kc0 * 8;

    const int r7 = lane15 & 7;
    // K fragment offsets (row = ni*16+lane15; row&7 == lane15&7): +ni*1024 u16
    int koff[2];
    #pragma unroll
    for (int kh = 0; kh < 2; ++kh)
        koff[kh] = (lane15 * 8 + ((kh * 4 + quad) ^ r7)) * 8;
    // V^T b64 fragment offsets
    int voff[4];
    #pragma unroll
    for (int ni = 0; ni < 4; ++ni)
        voff[ni] = (lane15 * 8 + ((ni * 2 + (quad >> 1)) ^ r7)) * 8 + (quad & 1) * 4;

    // Q fragments straight from global: elem j = Q[qrow][kh*32 + quad*8 + j]
    const int qrow = q0 + wave * 16 + lane15;
    bfrag bq[2];
    bq[0] = *(const bfrag*)(Qb + (size_t)qrow * HDIM + quad * 8);
    bq[1] = *(const bfrag*)(Qb + (size_t)qrow * HDIM + 32 + quad * 8);
    // drain Q loads so per-wave vmcnt counts only async16 tiles (2/tile)
    asm volatile("s_waitcnt vmcnt(0)" ::: "memory");

    // prologue staging: T0 -> buf0, T1 -> buf1 (depth 2). ktmax = 2*qt2+2 >= 2.
    async16(kga, &Ks[0][ldst]);
    async16(vga, &Vs[0][ldst]);
    async16(kga + 64 * HDIM, &Ks[1][ldst]);
    async16(vga + 64, &Vs[1][ldst]);
    // running pointers for tile 2 onward
    const u16* kpa = kga + 2 * 64 * HDIM;
    const u16* vpa = vga + 2 * 64;

    s16x4 ones4;
    #pragma unroll
    for (int i = 0; i < 4; ++i) ones4[i] = (short)0x3f80;   // bf16 1.0

    f32x4 acc_o[4];
    f32x4 acc_s = (f32x4){0.f, 0.f, 0.f, 0.f};
    #pragma unroll
    for (int nd = 0; nd < 4; ++nd) acc_o[nd] = (f32x4){0.f, 0.f, 0.f, 0.f};

    const int qg = qrow;          // this lane's absolute q row
    const int quad4 = quad * 4;
    const int ktd = 2 * qt2;      // first diagonal tile (masked for all)

    // tiles 0..ktd in the counted-vmcnt loop
    for (int kt = 0; kt <= ktd; ++kt) {
        // tile kt must be done; tile kt+1 (2 loads) may stay in flight
        asm volatile("s_waitcnt vmcnt(2)" ::: "memory");
        __builtin_amdgcn_s_barrier();      // all waves' tile-kt DMA visible
        if (kt < ktd)
            qkt_pv<false>(Ks[kt & 1], Vs[kt & 1], bq, koff, voff,
                          kt * 64, qg, quad4, acc_o, acc_s, ones4);
        else
            qkt_pv<true>(Ks[kt & 1], Vs[kt & 1], bq, koff, voff,
                         kt * 64, qg, quad4, acc_o, acc_s, ones4);
        __builtin_amdgcn_s_barrier();      // all waves done reading buf[kt&1]
        if (kt < ktd) {                    // stage tile kt+2 (<= ktd+1)
            async16(kpa, &Ks[kt & 1][ldst]);
            async16(vpa, &Vs[kt & 1][ldst]);
            kpa += 64 * HDIM;
            vpa += 64;
        }
    }
    // final tile ktd+1: rows q0+64..q0+127 only (waves 4..7)
    asm volatile("s_waitcnt vmcnt(0)" ::: "memory");
    __builtin_amdgcn_s_barrier();
    if (wave >= 4)
        qkt_pv<true>(Ks[(ktd + 1) & 1], Vs[(ktd + 1) & 1], bq, koff, voff,
                     (ktd + 1) * 64, qg, quad4, acc_o, acc_s, ones4);

    // epilogue: each lane owns one q row; acc_s rows are replicated row-sums
    const float inv = 1.f / acc_s[0];
    u16* dst = ctx + ((size_t)b * SS + qrow) * DD + h * HDIM + quad4;
    #pragma unroll
    for (int nd = 0; nd < 4; ++nd) {
        uint2 stw;
        stw.x = (unsigned)f2u(acc_o[nd][0] * inv) |
                ((unsigned)f2u(acc_o[nd][1] * inv) << 16);
        stw.y = (unsigned)f2u(acc_o[nd][2] * inv) |
                ((unsigned)f2u(acc_o[nd][3] * inv) << 16);
        *(uint2*)(dst + nd * 16) = stw;
    }
}

extern "C" void kernel_launch(void* const* d_in, const int* in_sizes, int n_in,
                              void* d_out, int out_size, void* d_ws, size_t ws_size,
                              hipStream_t stream) {
    const float* x  = (const float*)d_in[0];
    const float* wq = (const float*)d_in[1];
    const float* wk = (const float*)d_in[2];
    const float* wv = (const float*)d_in[3];
    const float* wo = (const float*)d_in[4];
    const float* bo = (const float*)d_in[5];
    float* out = (float*)d_out;

    char* ws = (char*)d_ws;
    const size_t MB8 = (size_t)8 * 1024 * 1024;
    u16* xb  = (u16*)(ws);             // 8MB; ctx reuses after qkv consumption
    u16* wT  = (u16*)(ws + MB8);       // 8MB
    u16* Qb  = (u16*)(ws + 2 * MB8);   // 8MB
    u16* Kb  = (u16*)(ws + 3 * MB8);   // 8MB
    u16* Vt  = (u16*)(ws + 4 * MB8);   // 8MB
    u16* ctxb = xb;

    prep_k    <<<3072, 256, 0, stream>>>(x, xb, wq, wk, wv, wo, wT);
    gemm_qkv_k<<<dim3(32, 16, 3), 256, 0, stream>>>(xb, wT, Qb, Kb, Vt);
    attn_k    <<<dim3(32, 16), 512, 0, stream>>>(Qb, Kb, Vt, ctxb);
    gemm_out_k<<<dim3(64, 16), 256, 0, stream>>>(ctxb, wT + (size_t)3 * DD * DD, bo, out);
}

// Round 10
// 166.855 us; speedup vs baseline: 1.0450x; 1.0450x over previous
//
#include <hip/hip_runtime.h>
#include <hip/hip_bf16.h>
#include <math.h>

#define BB 2
#define SS 2048
#define DD 1024
#define HH 16
#define HDIM 64

typedef unsigned short u16;
typedef __attribute__((ext_vector_type(8))) short bfrag;   // 8 bf16 = 4 VGPRs
typedef __attribute__((ext_vector_type(4))) short s16x4;   // 4 bf16 = 2 VGPRs
typedef __attribute__((ext_vector_type(4))) float f32x4;

#define NEG_BIG (-1e30f)
// 1/sqrt(64) * log2(e): folded into Q so attention uses exp2 directly
#define QSCALE 0.18033688011112042f

__device__ __forceinline__ u16 f2u(float f) {
    unsigned int u = __builtin_bit_cast(unsigned int, f);
    u += 0x7fffu + ((u >> 16) & 1u);
    return (u16)(u >> 16);
}

__device__ __forceinline__ float fexp2(float x) {
#if __has_builtin(__builtin_amdgcn_exp2f)
    return __builtin_amdgcn_exp2f(x);   // raw v_exp_f32 (TRANS pipe, 1 instr)
#else
    return exp2f(x);
#endif
}

__device__ __forceinline__ void async16(const u16* g, u16* l) {
    __builtin_amdgcn_global_load_lds((__attribute__((address_space(1))) void*)g,
                                     (__attribute__((address_space(3))) void*)l,
                                     16, 0, 0);
}

__device__ __forceinline__ f32x4 mfma16(bfrag a, bfrag b, f32x4 c) {
    return __builtin_amdgcn_mfma_f32_16x16x32_bf16(a, b, c, 0, 0, 0);
}

// 16x16x16 bf16 MFMA: builtin name differs across ROCm; dispatch at compile time.
__device__ __forceinline__ f32x4 mfma_pv(s16x4 a, s16x4 b, f32x4 c) {
#if __has_builtin(__builtin_amdgcn_mfma_f32_16x16x16_bf16)
    return __builtin_amdgcn_mfma_f32_16x16x16_bf16(a, b, c, 0, 0, 0);
#elif __has_builtin(__builtin_amdgcn_mfma_f32_16x16x16bf16_1k)
    return __builtin_amdgcn_mfma_f32_16x16x16bf16_1k(a, b, c, 0, 0, 0);
#else
    f32x4 d;
    asm("v_mfma_f32_16x16x16_bf16 %0, %1, %2, %3" : "=v"(d) : "v"(a), "v"(b), "v"(c));
    return d;
#endif
}

// ---------------------------------------------------------------------------
// prep: fused cvt_x + cvt_wT (round-0 verbatim).
// ---------------------------------------------------------------------------
__global__ __launch_bounds__(256) void prep_k(
    const float* __restrict__ x,  u16* __restrict__ xb,
    const float* __restrict__ wq, const float* __restrict__ wk,
    const float* __restrict__ wv, const float* __restrict__ wo,
    u16* __restrict__ wT)
{
    const int id = blockIdx.x;
    const int t = threadIdx.x;
    if (id < 2048) {
        int i = (id * 256 + t) * 8;
        float4 a = *(const float4*)(x + i);
        float4 b = *(const float4*)(x + i + 4);
        u16 o[8] = { f2u(a.x), f2u(a.y), f2u(a.z), f2u(a.w),
                     f2u(b.x), f2u(b.y), f2u(b.z), f2u(b.w) };
        *(uint4*)(xb + i) = *(uint4*)o;
        return;
    }
    const int wid = id - 2048;
    const int z = wid >> 8;
    const int kt = wid & 15, nt = (wid >> 4) & 15;
    const float* w = (z == 0) ? wq : (z == 1) ? wk : (z == 2) ? wv : wo;
    u16* o = wT + (size_t)z * DD * DD;
    __shared__ __align__(16) u16 T[64][72];
    const int k0 = kt * 64, n0 = nt * 64;
    {
        int kr = t >> 2, nb = (t & 3) * 16;
        const float4* s4 = (const float4*)(w + (size_t)(k0 + kr) * DD + n0 + nb);
        #pragma unroll
        for (int jj = 0; jj < 4; ++jj) {
            float4 v = s4[jj];
            T[kr][nb + jj*4 + 0] = f2u(v.x);
            T[kr][nb + jj*4 + 1] = f2u(v.y);
            T[kr][nb + jj*4 + 2] = f2u(v.z);
            T[kr][nb + jj*4 + 3] = f2u(v.w);
        }
    }
    __syncthreads();
    {
        int nr = t >> 2, kb = (t & 3) * 16;
        u16 tmp[16];
        #pragma unroll
        for (int j = 0; j < 16; ++j) tmp[j] = T[kb + j][nr];
        *(uint4*)(o + (size_t)(n0 + nr) * DD + k0 + kb)     = ((uint4*)tmp)[0];
        *(uint4*)(o + (size_t)(n0 + nr) * DD + k0 + kb + 8) = ((uint4*)tmp)[1];
    }
}

// ===========================================================================
// QKV GEMM (round-0 verbatim): BM=128, BN=64, BK=64 -> 1536 blocks.
// ===========================================================================
__global__ __launch_bounds__(256) void gemm_qkv_k(
    const u16* __restrict__ xb, const u16* __restrict__ wT,
    u16* __restrict__ Qo, u16* __restrict__ Ko, u16* __restrict__ Vt)
{
    const u16* wTz = wT + (size_t)blockIdx.z * DD * DD;
    const float osc = (blockIdx.z == 0) ? QSCALE : 1.0f;

    __shared__ __align__(16) u16 As[128 * 64];   // 16 KB
    __shared__ __align__(16) u16 Bs[64 * 64];    // 8 KB

    const int t = threadIdx.x;
    const int m0 = blockIdx.x * 128, n0 = blockIdx.y * 64;
    const int lane15 = t & 15, quad = (t >> 4) & 3, wave = t >> 6;
    const int wm = wave & 1, wn = wave >> 1;

    int arow[4], acol[4];
    #pragma unroll
    for (int i = 0; i < 4; ++i) {
        int c = t + i * 256;
        arow[i] = c >> 3;
        acol[i] = (c & 7) ^ (arow[i] & 7);
    }
    const int br0 = t >> 3,         bs0 = t & 7;
    const int br1 = (t + 256) >> 3, bs1 = (t + 256) & 7;
    const int bc0 = bs0 ^ (br0 & 7);
    const int bc1 = bs1 ^ (br1 & 7);
    const int ldb = (t & 192) * 8;

    int aoff[4][2], boff[2][2];
    #pragma unroll
    for (int mi = 0; mi < 4; ++mi) {
        int r = wm * 64 + mi * 16 + lane15;
        #pragma unroll
        for (int kh = 0; kh < 2; ++kh)
            aoff[mi][kh] = (r * 8 + ((kh * 4 + quad) ^ (r & 7))) * 8;
    }
    #pragma unroll
    for (int ni = 0; ni < 2; ++ni) {
        int r = wn * 32 + ni * 16 + lane15;
        #pragma unroll
        for (int kh = 0; kh < 2; ++kh)
            boff[ni][kh] = (r * 8 + ((kh * 4 + quad) ^ (r & 7))) * 8;
    }

    f32x4 acc[4][2];
    #pragma unroll
    for (int mi = 0; mi < 4; ++mi)
        #pragma unroll
        for (int ni = 0; ni < 2; ++ni)
            acc[mi][ni] = (f32x4){0.f, 0.f, 0.f, 0.f};

    for (int it = 0; it < 16; ++it) {
        const int k0 = it * 64;
        #pragma unroll
        for (int i = 0; i < 4; ++i)
            async16(xb + (size_t)(m0 + arow[i]) * DD + k0 + acol[i] * 8,
                    As + ldb + i * 2048);
        async16(wTz + (size_t)(n0 + br0) * DD + k0 + bc0 * 8, Bs + ldb);
        async16(wTz + (size_t)(n0 + br1) * DD + k0 + bc1 * 8, Bs + ldb + 2048);
        __syncthreads();
        #pragma unroll
        for (int kh = 0; kh < 2; ++kh) {
            bfrag av[4], bv[2];
            #pragma unroll
            for (int mi = 0; mi < 4; ++mi) av[mi] = *(const bfrag*)(As + aoff[mi][kh]);
            #pragma unroll
            for (int ni = 0; ni < 2; ++ni) bv[ni] = *(const bfrag*)(Bs + boff[ni][kh]);
            #pragma unroll
            for (int mi = 0; mi < 4; ++mi)
                #pragma unroll
                for (int ni = 0; ni < 2; ++ni)
                    acc[mi][ni] = mfma16(av[mi], bv[ni], acc[mi][ni]);
        }
        __syncthreads();
    }

    const int h = n0 >> 6;
    const int bq = m0 >> 11;
    const int ms = m0 & (SS - 1);

    if (blockIdx.z != 2) {
        u16* out = (blockIdx.z == 0) ? Qo : Ko;
        u16* dst = out + (((size_t)(bq * HH + h)) * SS) * HDIM;
        #pragma unroll
        for (int mi = 0; mi < 4; ++mi) {
            #pragma unroll
            for (int r = 0; r < 4; ++r) {
                int s = ms + wm * 64 + mi * 16 + quad * 4 + r;
                #pragma unroll
                for (int ni = 0; ni < 2; ++ni) {
                    int hd = wn * 32 + ni * 16 + lane15;
                    dst[(size_t)s * HDIM + hd] = f2u(acc[mi][ni][r] * osc);
                }
            }
        }
    } else {
        u16* T = As;
        __syncthreads();
        #pragma unroll
        for (int mi = 0; mi < 4; ++mi)
            #pragma unroll
            for (int r = 0; r < 4; ++r) {
                int ml = wm * 64 + mi * 16 + quad * 4 + r;
                #pragma unroll
                for (int ni = 0; ni < 2; ++ni) {
                    int nl = wn * 32 + ni * 16 + lane15;
                    T[nl * 128 + (ml ^ ((nl & 7) << 4))] = f2u(acc[mi][ni][r]);
                }
            }
        __syncthreads();
        u16* dst = Vt + ((size_t)(bq * HH + h)) * (HDIM * SS);
        #pragma unroll
        for (int i = 0; i < 4; ++i) {
            int c = t + i * 256;
            int row = c >> 4;
            int mb  = (c & 15) * 8;
            uint4 val = *(const uint4*)&T[row * 128 + (mb ^ ((row & 7) << 4))];
            *(uint4*)(dst + (size_t)row * SS + ms + mb) = val;
        }
    }
}

// ---------------------------------------------------------------------------
// Out projection (round-0 verbatim): BM=64, BN=64, BK=128 -> grid (64,16).
// ---------------------------------------------------------------------------
__global__ __launch_bounds__(256) void gemm_out_k(
    const u16* __restrict__ ctxb, const u16* __restrict__ woT,
    const float* __restrict__ bo, float* __restrict__ out)
{
    __shared__ __align__(16) u16 As[2][4096];    // [k-half][64x64]
    __shared__ __align__(16) u16 Bs[2][4096];

    const int t = threadIdx.x;
    const int m0 = blockIdx.x * 64, n0 = blockIdx.y * 64;
    const int lane15 = t & 15, quad = (t >> 4) & 3, wave = t >> 6;
    const int wm = wave & 1, wn = wave >> 1;

    const int br0 = t >> 3,         bs0 = t & 7;
    const int br1 = (t + 256) >> 3, bs1 = (t + 256) & 7;
    const int bc0 = bs0 ^ (br0 & 7);
    const int bc1 = bs1 ^ (br1 & 7);
    const int ldb = (t & 192) * 8;

    int aoff[2][2], boff[2][2];
    #pragma unroll
    for (int mi = 0; mi < 2; ++mi) {
        int r = wm * 32 + mi * 16 + lane15;
        #pragma unroll
        for (int kh = 0; kh < 2; ++kh)
            aoff[mi][kh] = (r * 8 + ((kh * 4 + quad) ^ (r & 7))) * 8;
    }
    #pragma unroll
    for (int ni = 0; ni < 2; ++ni) {
        int r = wn * 32 + ni * 16 + lane15;
        #pragma unroll
        for (int kh = 0; kh < 2; ++kh)
            boff[ni][kh] = (r * 8 + ((kh * 4 + quad) ^ (r & 7))) * 8;
    }

    f32x4 acc[2][2];
    #pragma unroll
    for (int mi = 0; mi < 2; ++mi)
        #pragma unroll
        for (int ni = 0; ni < 2; ++ni)
            acc[mi][ni] = (f32x4){0.f, 0.f, 0.f, 0.f};

    for (int it = 0; it < 8; ++it) {
        const int k0 = it * 128;
        #pragma unroll
        for (int hh = 0; hh < 2; ++hh) {
            const int kh64 = k0 + hh * 64;
            async16(ctxb + (size_t)(m0 + br0) * DD + kh64 + bc0 * 8, &As[hh][ldb]);
            async16(ctxb + (size_t)(m0 + br1) * DD + kh64 + bc1 * 8, &As[hh][ldb + 2048]);
            async16(woT  + (size_t)(n0 + br0) * DD + kh64 + bc0 * 8, &Bs[hh][ldb]);
            async16(woT  + (size_t)(n0 + br1) * DD + kh64 + bc1 * 8, &Bs[hh][ldb + 2048]);
        }
        __syncthreads();
        #pragma unroll
        for (int hh = 0; hh < 2; ++hh) {
            #pragma unroll
            for (int kh = 0; kh < 2; ++kh) {
                bfrag av[2], bv[2];
                #pragma unroll
                for (int mi = 0; mi < 2; ++mi) av[mi] = *(const bfrag*)&As[hh][aoff[mi][kh]];
                #pragma unroll
                for (int ni = 0; ni < 2; ++ni) bv[ni] = *(const bfrag*)&Bs[hh][boff[ni][kh]];
                #pragma unroll
                for (int mi = 0; mi < 2; ++mi)
                    #pragma unroll
                    for (int ni = 0; ni < 2; ++ni)
                        acc[mi][ni] = mfma16(av[mi], bv[ni], acc[mi][ni]);
            }
        }
        __syncthreads();
    }

    float bias[2];
    #pragma unroll
    for (int ni = 0; ni < 2; ++ni)
        bias[ni] = bo[n0 + wn * 32 + ni * 16 + lane15];

    #pragma unroll
    for (int mi = 0; mi < 2; ++mi) {
        #pragma unroll
        for (int r = 0; r < 4; ++r) {
            int m = m0 + wm * 32 + mi * 16 + quad * 4 + r;
            #pragma unroll
            for (int ni = 0; ni < 2; ++ni) {
                int n = n0 + wn * 32 + ni * 16 + lane15;
                out[(size_t)m * DD + n] = acc[mi][ni][r] + bias[ni];
            }
        }
    }
}

// ===========================================================================
// MFMA flash attention — 128-row Q x 128-col KV tiles (8 waves, 512 thr).
// Per-CU block-iterations: 17 (was 34 at KVBLK=64, 66 at r6). Diagonal is
// the single tile kt==qt2 (no split tail). LDS 64 KB -> 2 blocks/CU,
// 4 waves/SIMD. Counted-vmcnt depth-2 in two buffers: per iter
// vmcnt(4) -> barrier -> compute -> barrier -> restage (4 loads/tile).
// K LDS [128 rows][8 slots], V^T LDS [64 rows][16 slots], XOR swizzle in
// the low 3 slot bits on both write-source and read (both-sides rule).
// ===========================================================================
template<bool MASKED>
__device__ __forceinline__ void qkt_pv(
    const u16* __restrict__ Kc, const u16* __restrict__ Vc,
    const bfrag bq[2], const int koff[2], const int voff[8],
    int kv0, int qg, int quad4, f32x4 acc_o[4], f32x4& acc_s, s16x4 ones4)
{
    f32x4 sT[8];
    #pragma unroll
    for (int ni = 0; ni < 8; ++ni) sT[ni] = (f32x4){0.f, 0.f, 0.f, 0.f};

    __builtin_amdgcn_s_setprio(1);
    #pragma unroll
    for (int kh = 0; kh < 2; ++kh)
        #pragma unroll
        for (int ni = 0; ni < 8; ++ni)
            sT[ni] = mfma16(*(const bfrag*)&Kc[koff[kh] + ni * 1024], bq[kh], sT[ni]);
    __builtin_amdgcn_s_setprio(0);

    #pragma unroll
    for (int ni = 0; ni < 8; ++ni) {
        float pv[4];
        #pragma unroll
        for (int r = 0; r < 4; ++r) {
            float v = sT[ni][r];
            if (MASKED) {
                int kvg = kv0 + ni * 16 + quad4 + r;
                if (kvg > qg) v = NEG_BIG;
            }
            pv[r] = fexp2(v);
        }
        unsigned lo = __builtin_amdgcn_perm(
            __builtin_bit_cast(unsigned, pv[1]),
            __builtin_bit_cast(unsigned, pv[0]), 0x07060302u);
        unsigned hi = __builtin_amdgcn_perm(
            __builtin_bit_cast(unsigned, pv[3]),
            __builtin_bit_cast(unsigned, pv[2]), 0x07060302u);
        s16x4 pf = __builtin_bit_cast(s16x4,
            ((unsigned long long)hi << 32) | (unsigned long long)lo);
        __builtin_amdgcn_s_setprio(1);
        acc_s = mfma_pv(ones4, pf, acc_s);
        #pragma unroll
        for (int nd = 0; nd < 4; ++nd)
            acc_o[nd] = mfma_pv(*(const s16x4*)&Vc[voff[ni] + nd * 2048],
                                pf, acc_o[nd]);
        __builtin_amdgcn_s_setprio(0);
    }
}

__global__ __launch_bounds__(512, 4) void attn_k(
    const u16* __restrict__ Q, const u16* __restrict__ K,
    const u16* __restrict__ Vt, u16* __restrict__ ctx)
{
    __shared__ __align__(16) u16 Ks[2][128 * 64];   // 32 KB
    __shared__ __align__(16) u16 Vs[2][64 * 128];   // 32 KB
    const int t = threadIdx.x;
    const int lane15 = t & 15, quad = (t >> 4) & 3, wave = t >> 6;   // wave 0..7
    const int bh = blockIdx.x;
    // balanced pairing: y 0..7 -> qt2 = 15-y0 (long), y 8..15 -> qt2 = y0.
    const int yy = (int)blockIdx.y;
    const int y0 = yy & 7;
    const int qt2 = (yy >> 3) ? y0 : 15 - y0;
    const int q0 = qt2 * 128;
    const int b = bh >> 4, h = bh & 15;
    const u16* Qb = Q  + (size_t)bh * SS * HDIM;
    const u16* Kb = K  + (size_t)bh * SS * HDIM;
    const u16* Vb = Vt + (size_t)bh * HDIM * SS;

    // --- staging sources (dest is always linear: wave base + lane*16B) ---
    // K round 1: row t>>3 (0..63), slot (t&7)^(row&7); round 2: +64 rows.
    const int kr = t >> 3;
    const u16* kga = Kb + (size_t)kr * HDIM + ((t & 7) ^ (kr & 7)) * 8;
    // V round 1: row t>>4 (0..31), 16-slot swizzle in low 3 bits; round 2: +32.
    const int vr = t >> 4;
    const u16* vga = Vb + (size_t)vr * SS + ((((t & 7) ^ (vr & 7)) | (t & 8)) * 8);
    const int ldst = (t & 448) * 8;     // wave-uniform LDS base (u16)

    const int r7 = lane15 & 7;
    // K fragment offsets: row = ni*16+lane15, 8-slot rows -> +ni*1024 u16
    int koff[2];
    #pragma unroll
    for (int kh = 0; kh < 2; ++kh)
        koff[kh] = (lane15 * 8 + ((kh * 4 + quad) ^ r7)) * 8;
    // V^T fragment offsets: row = nd*16+lane15 (128-u16 rows), slot 0..15;
    // XOR r7 touches only low 3 bits (bit3 = ni>=4 preserved).
    int voff[8];
    #pragma unroll
    for (int ni = 0; ni < 8; ++ni)
        voff[ni] = lane15 * 128 + ((ni * 2 + (quad >> 1)) ^ r7) * 8 + (quad & 1) * 4;

    // Q fragments straight from global: elem j = Q[qrow][kh*32 + quad*8 + j]
    const int qrow = q0 + wave * 16 + lane15;
    bfrag bq[2];
    bq[0] = *(const bfrag*)(Qb + (size_t)qrow * HDIM + quad * 8);
    bq[1] = *(const bfrag*)(Qb + (size_t)qrow * HDIM + 32 + quad * 8);
    // drain Q loads so vmcnt counts only async16 staging (4 loads/tile)
    asm volatile("s_waitcnt vmcnt(0)" ::: "memory");

    // prologue staging: tile 0 -> buf0 (4 loads), tile 1 -> buf1 (4 loads)
    async16(kga,                 &Ks[0][ldst]);
    async16(kga + 64 * HDIM,     &Ks[0][ldst + 4096]);
    async16(vga,                 &Vs[0][ldst]);
    async16(vga + 32 * SS,       &Vs[0][ldst + 4096]);
    if (qt2 >= 1) {
        async16(kga + 128 * HDIM,      &Ks[1][ldst]);
        async16(kga + 192 * HDIM,      &Ks[1][ldst + 4096]);
        async16(vga + 128,             &Vs[1][ldst]);
        async16(vga + 32 * SS + 128,   &Vs[1][ldst + 4096]);
    }
    // running pointers for tile 2 onward
    const u16* kpa = kga + 2 * 128 * HDIM;
    const u16* vpa = vga + 2 * 128;

    s16x4 ones4;
    #pragma unroll
    for (int i = 0; i < 4; ++i) ones4[i] = (short)0x3f80;   // bf16 1.0

    f32x4 acc_o[4];
    f32x4 acc_s = (f32x4){0.f, 0.f, 0.f, 0.f};
    #pragma unroll
    for (int nd = 0; nd < 4; ++nd) acc_o[nd] = (f32x4){0.f, 0.f, 0.f, 0.f};

    const int qg = qrow;
    const int quad4 = quad * 4;

    // off-diagonal tiles (kt < qt2): counted-vmcnt, two buffers
    for (int kt = 0; kt < qt2; ++kt) {
        // in flight: tiles kt + kt+1 = 8 loads; allow kt+1's 4 to stay out
        asm volatile("s_waitcnt vmcnt(4)" ::: "memory");
        __builtin_amdgcn_s_barrier();      // all waves' tile-kt DMA visible
        qkt_pv<false>(Ks[kt & 1], Vs[kt & 1], bq, koff, voff,
                      kt * 128, qg, quad4, acc_o, acc_s, ones4);
        __builtin_amdgcn_s_barrier();      // all waves done reading buf[kt&1]
        if (kt + 2 <= qt2) {               // restage buf[kt&1] with tile kt+2
            async16(kpa,             &Ks[kt & 1][ldst]);
            async16(kpa + 64 * HDIM, &Ks[kt & 1][ldst + 4096]);
            async16(vpa,             &Vs[kt & 1][ldst]);
            async16(vpa + 32 * SS,   &Vs[kt & 1][ldst + 4096]);
            kpa += 128 * HDIM;
            vpa += 128;
        }
    }
    // diagonal tile kt == qt2 (masked): drain everything
    asm volatile("s_waitcnt vmcnt(0)" ::: "memory");
    __builtin_amdgcn_s_barrier();
    qkt_pv<true>(Ks[qt2 & 1], Vs[qt2 & 1], bq, koff, voff,
                 qt2 * 128, qg, quad4, acc_o, acc_s, ones4);

    // epilogue: each lane owns one q row; acc_s rows are replicated row-sums
    const float inv = 1.f / acc_s[0];
    u16* dst = ctx + ((size_t)b * SS + qrow) * DD + h * HDIM + quad4;
    #pragma unroll
    for (int nd = 0; nd < 4; ++nd) {
        uint2 stw;
        stw.x = (unsigned)f2u(acc_o[nd][0] * inv) |
                ((unsigned)f2u(acc_o[nd][1] * inv) << 16);
        stw.y = (unsigned)f2u(acc_o[nd][2] * inv) |
                ((unsigned)f2u(acc_o[nd][3] * inv) << 16);
        *(uint2*)(dst + nd * 16) = stw;
    }
}

extern "C" void kernel_launch(void* const* d_in, const int* in_sizes, int n_in,
                              void* d_out, int out_size, void* d_ws, size_t ws_size,
                              hipStream_t stream) {
    const float* x  = (const float*)d_in[0];
    const float* wq = (const float*)d_in[1];
    const float* wk = (const float*)d_in[2];
    const float* wv = (const float*)d_in[3];
    const float* wo = (const float*)d_in[4];
    const float* bo = (const float*)d_in[5];
    float* out = (float*)d_out;

    char* ws = (char*)d_ws;
    const size_t MB8 = (size_t)8 * 1024 * 1024;
    u16* xb  = (u16*)(ws);             // 8MB; ctx reuses after qkv consumption
    u16* wT  = (u16*)(ws + MB8);       // 8MB
    u16* Qb  = (u16*)(ws + 2 * MB8);   // 8MB
    u16* Kb  = (u16*)(ws + 3 * MB8);   // 8MB
    u16* Vt  = (u16*)(ws + 4 * MB8);   // 8MB
    u16* ctxb = xb;

    prep_k    <<<3072, 256, 0, stream>>>(x, xb, wq, wk, wv, wo, wT);
    gemm_qkv_k<<<dim3(32, 16, 3), 256, 0, stream>>>(xb, wT, Qb, Kb, Vt);
    attn_k    <<<dim3(32, 16), 512, 0, stream>>>(Qb, Kb, Vt, ctxb);
    gemm_out_k<<<dim3(64, 16), 256, 0, stream>>>(ctxb, wT + (size_t)3 * DD * DD, bo, out);
}